// Round 2
// baseline (413.062 us; speedup 1.0000x reference)
//
#include <hip/hip_runtime.h>
#include <hip/hip_bf16.h>

// Problem constants
#define HW    50176            // 224*224
#define IMGW  224
#define SEG   196              // R*R
#define NBATCH 128
#define NCOL  (NBATCH * SEG)   // 25088 rows (pixels) of every GEMM
#define PB    14               // accumulation blocks per batch image
#define CHUNK (HW / PB)        // 3584 pixels per block
#define VCHUNK (CHUNK / 4)     // 896 float4 groups per block

typedef __attribute__((ext_vector_type(8))) short bf16x8;   // 8 bf16 = 4 VGPRs
typedef __attribute__((ext_vector_type(4))) float f32x4;
typedef unsigned long long u64;

static __device__ __forceinline__ ushort f2bf(float v) {
    __hip_bfloat16 h = __float2bfloat16(v);
    return *reinterpret_cast<ushort*>(&h);
}

// ---------------------------------------------------------------------------
// Kernel 1: segmented accumulation via packed u64 LDS atomics (4 per pixel).
// ---------------------------------------------------------------------------
__global__ __launch_bounds__(256) void seg_accum(const float* __restrict__ x,
                                                 const int*   __restrict__ sl,
                                                 float*       __restrict__ stats) {
    __shared__ u64 ls[4][SEG];
    int b    = blockIdx.x / PB;
    int part = blockIdx.x % PB;
    int tid  = threadIdx.x;

    for (int i = tid; i < 4 * SEG; i += 256) (&ls[0][0])[i] = 0ull;
    __syncthreads();

    const float* xb = x + (size_t)b * 3 * HW;
    const int*   sb = sl + (size_t)b * HW;
    int v0 = part * VCHUNK;

    for (int vi = tid; vi < VCHUNK; vi += 256) {
        int vg = v0 + vi;                 // float4 group index in image
        int4   id4 = ((const int4*)sb)[vg];
        float4 r4  = ((const float4*)xb)[vg];
        float4 g4  = ((const float4*)(xb + HW))[vg];
        float4 b4  = ((const float4*)(xb + 2 * HW))[vg];
        int p   = vg * 4;
        int row = p / IMGW;               // 4 | 224 -> all 4 pixels same row
        int col = p - row * IMGW;
        u64 rowbits = ((u64)1 << 48) | ((u64)(unsigned)row << 24);

#pragma unroll
        for (int q = 0; q < 4; ++q) {
            int   id = (q == 0) ? id4.x : (q == 1) ? id4.y : (q == 2) ? id4.z : id4.w;
            float r  = (q == 0) ? r4.x  : (q == 1) ? r4.y  : (q == 2) ? r4.z  : r4.w;
            float g  = (q == 0) ? g4.x  : (q == 1) ? g4.y  : (q == 2) ? g4.z  : g4.w;
            float bl = (q == 0) ? b4.x  : (q == 1) ? b4.y  : (q == 2) ? b4.z  : b4.w;

            unsigned qr  = (unsigned)fmaf(r,  8192.f, 131072.5f);   // (r+16)*8192
            unsigned qg  = (unsigned)fmaf(g,  8192.f, 131072.5f);
            unsigned qb  = (unsigned)fmaf(bl, 8192.f, 131072.5f);
            unsigned qr2 = (unsigned)fmaf(r * r,  2048.f, 0.5f);
            unsigned qg2 = (unsigned)fmaf(g * g,  2048.f, 0.5f);
            unsigned qb2 = (unsigned)fmaf(bl * bl, 2048.f, 0.5f);

            atomicAdd(&ls[0][id], rowbits | (unsigned)(col + q));
            atomicAdd(&ls[1][id], ((u64)qg  << 32) | qr);
            atomicAdd(&ls[2][id], ((u64)qr2 << 32) | qb);
            atomicAdd(&ls[3][id], ((u64)qb2 << 32) | qg2);
        }
    }
    __syncthreads();

    const float inv_s = 1.f / 8192.f, inv_q = 1.f / 2048.f;
    for (int i = tid; i < SEG; i += 256) {
        u64 v0p = ls[0][i];
        unsigned cnt = (unsigned)(v0p >> 48);
        if (!cnt) continue;
        float fc   = (float)cnt;
        float rows = (float)((unsigned)(v0p >> 24) & 0xFFFFFFu);
        float cols = (float)((unsigned)v0p & 0xFFFFFFu);
        u64 v1 = ls[1][i], v2 = ls[2][i], v3 = ls[3][i];
        float bias = 16.f * fc;
        float rsum = (float)(unsigned)v1         * inv_s - bias;
        float gsum = (float)(unsigned)(v1 >> 32) * inv_s - bias;
        float bsum = (float)(unsigned)v2         * inv_s - bias;
        float rsq  = (float)(unsigned)(v2 >> 32) * inv_q;
        float gsq  = (float)(unsigned)v3         * inv_q;
        float bsq  = (float)(unsigned)(v3 >> 32) * inv_q;

        size_t base = (size_t)b * SEG + i;
        atomicAdd(&stats[0 * NCOL + base], fc);
        atomicAdd(&stats[1 * NCOL + base], rows);
        atomicAdd(&stats[2 * NCOL + base], cols);
        atomicAdd(&stats[3 * NCOL + base], rsum);
        atomicAdd(&stats[4 * NCOL + base], gsum);
        atomicAdd(&stats[5 * NCOL + base], bsum);
        atomicAdd(&stats[6 * NCOL + base], rsq);
        atomicAdd(&stats[7 * NCOL + base], gsq);
        atomicAdd(&stats[8 * NCOL + base], bsq);
    }
}

// ---------------------------------------------------------------------------
// Kernel 2: 11 features -> bf16 F[n][64] (cols 11..63 zero). n = b*SEG+s.
// F is plain row-major; gemm_mfma's staging applies XOR on the SOURCE address
// and un-XORs on the fragment read, so plain row-major is what it expects.
// ---------------------------------------------------------------------------
__global__ __launch_bounds__(256) void feat_build(const float* __restrict__ x,
                                                  const float* __restrict__ stats,
                                                  ushort*      __restrict__ F) {
    int n = blockIdx.x * 256 + threadIdx.x;
    if (n >= NCOL) return;
    int b = n / SEG;

    float cnt  = stats[n];
    float safe = fmaxf(cnt, 1.f);
    float inv  = 1.f / safe;
    float mrow = stats[1 * NCOL + n] * inv;
    float mcol = stats[2 * NCOL + n] * inv;
    float mr   = stats[3 * NCOL + n] * inv;
    float mg   = stats[4 * NCOL + n] * inv;
    float mb   = stats[5 * NCOL + n] * inv;
    float den  = fmaxf(cnt - 1.f, 1.f);
    float vr = (stats[6 * NCOL + n] - cnt * mr * mr) / den;
    float vg = (stats[7 * NCOL + n] - cnt * mg * mg) / den;
    float vb = (stats[8 * NCOL + n] - cnt * mb * mb) / den;
    bool  has2 = cnt > 1.f;
    float sr = has2 ? sqrtf(fmaxf(vr, 0.f)) : 0.f;
    float sg = has2 ? sqrtf(fmaxf(vg, 0.f)) : 0.f;
    float sb = has2 ? sqrtf(fmaxf(vb, 0.f)) : 0.f;

    int ri = min(max((int)mrow, 0), IMGW - 1);
    int ci = min(max((int)mcol, 0), IMGW - 1);
    const float* xb = x + (size_t)b * 3 * HW;
    int pi = ri * IMGW + ci;
    float gr = xb[pi], gg = xb[HW + pi], gb = xb[2 * HW + pi];

    float mask = cnt > 0.f ? 1.f : 0.f;
    ushort* Fr = F + (size_t)n * 64;
#pragma unroll
    for (int k = 11; k < 64; ++k) Fr[k] = 0;
    Fr[0]  = f2bf(mrow * mask);
    Fr[1]  = f2bf(mcol * mask);
    Fr[2]  = f2bf(mr * mask);
    Fr[3]  = f2bf(mg * mask);
    Fr[4]  = f2bf(mb * mask);
    Fr[5]  = f2bf(sr * mask);
    Fr[6]  = f2bf(sg * mask);
    Fr[7]  = f2bf(sb * mask);
    Fr[8]  = f2bf(gr * mask);
    Fr[9]  = f2bf(gg * mask);
    Fr[10] = f2bf(gb * mask);
}

// ---------------------------------------------------------------------------
// Kernel 3: weight convert fp32 (Cout,K) -> bf16 padded (Opad,Kpad), zero pads
// ---------------------------------------------------------------------------
__global__ __launch_bounds__(256) void convert_w(const float* __restrict__ src,
                                                 ushort* __restrict__ dst,
                                                 int Cout, int K, int Kpad, int total) {
    int i = blockIdx.x * 256 + threadIdx.x;
    if (i >= total) return;
    int o = i / Kpad, k = i - o * Kpad;
    float v = (o < Cout && k < K) ? src[(size_t)o * K + k] : 0.f;
    dst[i] = f2bf(v);
}

// ---------------------------------------------------------------------------
// Kernel 4: bf16 MFMA GEMM + folded BN (+ReLU), XOR-swizzled LDS.
// C[n][o] = act(alpha[o] * sum_k Aact[n][k]*Wb[o][k] + beta[o])
// Block 128(n) x 128(o), BK=64, 4 waves in 2x2, 4x4 16x16x32 frags per wave.
//
// Round 1: guide's proven minimal 2-phase double-buffer (T3 recipe, m230):
//   prologue: stage(buf0,0); vmcnt(0); barrier
//   iter t:   stage(buf^1,t+1); compute(buf); vmcnt(0); barrier; buf^=1
//   epilogue: compute(buf)  (no prefetch)
// One s_barrier per K-tile; tile t+1's global->LDS latency hides under
// tile t's 32 MFMAs. Race-free: stage(buf^1) overwrites a buffer all waves
// finished reading before the PREVIOUS iteration's barrier.
// Plus bijective XCD swizzle (m204) so o-tiles sharing one A row-panel are
// consecutive on the same XCD -> A panel served from that XCD's L2.
// ---------------------------------------------------------------------------
__global__ __launch_bounds__(256) void gemm_mfma(const ushort* __restrict__ Aact,
                                                 const ushort* __restrict__ Wb,
                                                 void* __restrict__ outp,
                                                 const float* __restrict__ bias,
                                                 const float* __restrict__ gam,
                                                 const float* __restrict__ bet,
                                                 const float* __restrict__ rm,
                                                 const float* __restrict__ rv,
                                                 int Kpad, int Cout, int OutStride,
                                                 int act, int final_out) {
    __shared__ ushort As[2][128 * 64];   // [buf][n][k-slot]
    __shared__ ushort Bs[2][128 * 64];   // [buf][o][k-slot]

    int tid  = threadIdx.x;
    int lane = tid & 63;
    int wid  = tid >> 6;
    int wm   = wid & 1;               // wave row (n)
    int wn   = wid >> 1;              // wave col (o)

    // --- XCD-aware bijective remap (m204): dispatch id -> logical (row,o)
    // with the o index fastest, so the nby blocks reusing one A row-panel
    // are consecutive logical ids on the SAME XCD.
    int nbx  = gridDim.x, nby = gridDim.y;
    int nwg  = nbx * nby;
    int orig = blockIdx.y * nbx + blockIdx.x;
    int xcd  = orig & 7;
    int q    = nwg >> 3, r = nwg & 7;
    int wgid = (xcd < r ? xcd * (q + 1) : r * (q + 1) + (xcd - r) * q) + (orig >> 3);
    int bx   = wgid / nby;            // row tile
    int by   = wgid - bx * nby;       // o tile
    int n0   = bx * 128;
    int o0   = by * 128;

    int mrow = lane & 15;
    int quad = lane >> 4;
    int swz  = mrow & 7;              // row-dependent XOR for fragment reads

    f32x4 acc[4][4];
#pragma unroll
    for (int i = 0; i < 4; ++i)
#pragma unroll
        for (int j = 0; j < 4; ++j) acc[i][j] = (f32x4){0.f, 0.f, 0.f, 0.f};

    // Per-thread staging addresses (source XOR-swizzled, dest linear).
    const ushort* aSrc[4];
    const ushort* bSrc[4];
    int ldsDst[4];
#pragma unroll
    for (int p = 0; p < 4; ++p) {
        int flat = p * 256 + tid;
        int row  = flat >> 3, kg = flat & 7;
        int kgs  = kg ^ (row & 7);
        aSrc[p]  = Aact + (size_t)(n0 + row) * Kpad + kgs * 8;
        bSrc[p]  = Wb   + (size_t)(o0 + row) * Kpad + kgs * 8;
        ldsDst[p] = (p * 256 + wid * 64) * 8;
    }

    auto stage = [&](int buf, int kt) {
        int kb = kt * 64;
#pragma unroll
        for (int p = 0; p < 4; ++p)
            __builtin_amdgcn_global_load_lds(
                (const __attribute__((address_space(1))) void*)(aSrc[p] + kb),
                (__attribute__((address_space(3))) void*)(&As[buf][ldsDst[p]]),
                16, 0, 0);
#pragma unroll
        for (int p = 0; p < 4; ++p)
            __builtin_amdgcn_global_load_lds(
                (const __attribute__((address_space(1))) void*)(bSrc[p] + kb),
                (__attribute__((address_space(3))) void*)(&Bs[buf][ldsDst[p]]),
                16, 0, 0);
    };

    auto compute = [&](int buf) {
#pragma unroll
        for (int ks = 0; ks < 2; ++ks) {
            bf16x8 af[4], bfr[4];
            int gbase = ks * 4 + quad;           // logical 16B group 0..7
            int slot  = (gbase ^ swz) * 8;       // swizzled element offset
#pragma unroll
            for (int i = 0; i < 4; ++i)
                af[i] = *(const bf16x8*)&As[buf][(size_t)(wm * 64 + i * 16 + mrow) * 64 + slot];
#pragma unroll
            for (int j = 0; j < 4; ++j)
                bfr[j] = *(const bf16x8*)&Bs[buf][(size_t)(wn * 64 + j * 16 + mrow) * 64 + slot];
#pragma unroll
            for (int i = 0; i < 4; ++i)
#pragma unroll
                for (int j = 0; j < 4; ++j)
                    acc[i][j] = __builtin_amdgcn_mfma_f32_16x16x32_bf16(af[i], bfr[j], acc[i][j], 0, 0, 0);
        }
    };

    int ktiles = Kpad >> 6;

    // Prologue: stage tile 0, full drain, barrier.
    stage(0, 0);
    asm volatile("s_waitcnt vmcnt(0)" ::: "memory");
    __builtin_amdgcn_s_barrier();

    int cur = 0;
    for (int t = 0; t < ktiles - 1; ++t) {
        stage(cur ^ 1, t + 1);                     // issue next tile's loads
        compute(cur);                              // MFMA on current tile
        asm volatile("s_waitcnt vmcnt(0)" ::: "memory");  // next tile landed
        __builtin_amdgcn_s_barrier();
        cur ^= 1;
    }
    compute(cur);                                  // last tile, no prefetch

    // epilogue: C row = n (quad*4+reg), col = o (lane&15)
#pragma unroll
    for (int j = 0; j < 4; ++j) {
        int o = o0 + wn * 64 + j * 16 + mrow;
        float al = 0.f, bt = 0.f;
        if (o < Cout) {
            float sc = gam[o] / sqrtf(rv[o] + 1e-5f);
            al = sc;
            bt = (bias[o] - rm[o]) * sc + bet[o];
        }
#pragma unroll
        for (int i = 0; i < 4; ++i) {
            int nbase = n0 + wm * 64 + i * 16 + quad * 4;
#pragma unroll
            for (int rr = 0; rr < 4; ++rr) {
                float v = acc[i][j][rr] * al + bt;
                if (act) v = fmaxf(v, 0.f);
                int n = nbase + rr;
                if (final_out) {
                    int b = n / SEG, s = n - b * SEG;
                    ((float*)outp)[(size_t)b * 768 * SEG + (size_t)o * SEG + s] = v;
                } else {
                    ((ushort*)outp)[(size_t)n * OutStride + o] = f2bf(v);
                }
            }
        }
    }
}

// ---------------------------------------------------------------------------
// Kernel 5: copy sliced (int32) -> out as float values
// ---------------------------------------------------------------------------
__global__ __launch_bounds__(256) void copy_sliced(const int4* __restrict__ sl,
                                                   float4* __restrict__ out) {
    int i = blockIdx.x * 256 + threadIdx.x;
    int4 v = sl[i];
    out[i] = make_float4((float)v.x, (float)v.y, (float)v.z, (float)v.w);
}

// ---------------------------------------------------------------------------
extern "C" void kernel_launch(void* const* d_in, const int* in_sizes, int n_in,
                              void* d_out, int out_size, void* d_ws, size_t ws_size,
                              hipStream_t stream) {
    const float* x  = (const float*)d_in[0];
    const int*   sl = (const int*)d_in[1];
    const float* Wp[5], *Bp[5], *Gp[5], *BEp[5], *RMp[5], *RVp[5];
    for (int i = 0; i < 5; ++i) {
        Wp[i]  = (const float*)d_in[2 + 6 * i + 0];
        Bp[i]  = (const float*)d_in[2 + 6 * i + 1];
        Gp[i]  = (const float*)d_in[2 + 6 * i + 2];
        BEp[i] = (const float*)d_in[2 + 6 * i + 3];
        RMp[i] = (const float*)d_in[2 + 6 * i + 4];
        RVp[i] = (const float*)d_in[2 + 6 * i + 5];
    }
    float* out = (float*)d_out;

    // layer geometry: Kpad (=prev Opad), Kreal, Cout, Opad
    const int Kpad[5]  = {64, 128, 256, 384, 768};
    const int Kreal[5] = {11, 96, 192, 384, 768};
    const int Cout[5]  = {96, 192, 384, 768, 768};
    const int Opad[5]  = {128, 256, 384, 768, 768};

    // workspace layout
    char* wsb = (char*)d_ws;
    float*  stats = (float*)wsb;                        // 9*NCOL fp32
    wsb += (size_t)9 * NCOL * sizeof(float);
    ushort* F = (ushort*)wsb;                           // NCOL x 64 bf16
    wsb += (size_t)NCOL * 64 * sizeof(ushort);
    ushort* Wpad[5];
    for (int i = 0; i < 5; ++i) {
        Wpad[i] = (ushort*)wsb;
        wsb += (size_t)Opad[i] * Kpad[i] * sizeof(ushort);
    }
    ushort* bufA = (ushort*)wsb;                        // NCOL x 384 bf16 max
    wsb += (size_t)NCOL * 384 * sizeof(ushort);
    ushort* bufB = (ushort*)wsb;                        // NCOL x 768 bf16

    hipMemsetAsync(stats, 0, (size_t)9 * NCOL * sizeof(float), stream);

    for (int i = 0; i < 5; ++i) {
        int total = Opad[i] * Kpad[i];
        convert_w<<<(total + 255) / 256, 256, 0, stream>>>(
            Wp[i], Wpad[i], Cout[i], Kreal[i], Kpad[i], total);
    }

    seg_accum<<<NBATCH * PB, 256, 0, stream>>>(x, sl, stats);
    feat_build<<<(NCOL + 255) / 256, 256, 0, stream>>>(x, stats, F);

    const int NT = NCOL / 128;  // 196 row tiles
    // L0: 11(64) -> 96(128), relu
    gemm_mfma<<<dim3(NT, Opad[0] / 128), 256, 0, stream>>>(
        F, Wpad[0], bufA, Bp[0], Gp[0], BEp[0], RMp[0], RVp[0],
        Kpad[0], Cout[0], Opad[0], 1, 0);
    // L1: 96(128) -> 192(256), relu
    gemm_mfma<<<dim3(NT, Opad[1] / 128), 256, 0, stream>>>(
        bufA, Wpad[1], bufB, Bp[1], Gp[1], BEp[1], RMp[1], RVp[1],
        Kpad[1], Cout[1], Opad[1], 1, 0);
    // L2: 192(256) -> 384, relu
    gemm_mfma<<<dim3(NT, Opad[2] / 128), 256, 0, stream>>>(
        bufB, Wpad[2], bufA, Bp[2], Gp[2], BEp[2], RMp[2], RVp[2],
        Kpad[2], Cout[2], Opad[2], 1, 0);
    // L3: 384 -> 768, relu
    gemm_mfma<<<dim3(NT, Opad[3] / 128), 256, 0, stream>>>(
        bufA, Wpad[3], bufB, Bp[3], Gp[3], BEp[3], RMp[3], RVp[3],
        Kpad[3], Cout[3], Opad[3], 1, 0);
    // L4: 768 -> 768, no act, fp32 out at offset B*H*W in (b,768,196) layout
    gemm_mfma<<<dim3(NT, Opad[4] / 128), 256, 0, stream>>>(
        bufB, Wpad[4], out + (size_t)NBATCH * HW, Bp[4], Gp[4], BEp[4], RMp[4], RVp[4],
        Kpad[4], Cout[4], 0, 0, 1);

    // output 0: sliced as float
    copy_sliced<<<(NBATCH * HW / 4) / 256, 256, 0, stream>>>((const int4*)sl,
                                                             (float4*)out);
}

// Round 3
// 411.000 us; speedup vs baseline: 1.0050x; 1.0050x over previous
//
#include <hip/hip_runtime.h>
#include <hip/hip_bf16.h>

// Problem constants
#define HW    50176            // 224*224
#define IMGW  224
#define SEG   196              // R*R
#define NBATCH 128
#define NCOL  (NBATCH * SEG)   // 25088 rows (pixels) of every GEMM
#define PB    14               // accumulation blocks per batch image
#define CHUNK (HW / PB)        // 3584 pixels per block
#define VCHUNK (CHUNK / 4)     // 896 float4 groups per block

typedef __attribute__((ext_vector_type(8))) short bf16x8;   // 8 bf16 = 4 VGPRs
typedef __attribute__((ext_vector_type(4))) float f32x4;
typedef unsigned long long u64;

static __device__ __forceinline__ ushort f2bf(float v) {
    __hip_bfloat16 h = __float2bfloat16(v);
    return *reinterpret_cast<ushort*>(&h);
}

// ---------------------------------------------------------------------------
// Kernel 1: segmented accumulation via packed u64 LDS atomics (4 per pixel).
// ---------------------------------------------------------------------------
__global__ __launch_bounds__(256) void seg_accum(const float* __restrict__ x,
                                                 const int*   __restrict__ sl,
                                                 float*       __restrict__ stats) {
    __shared__ u64 ls[4][SEG];
    int b    = blockIdx.x / PB;
    int part = blockIdx.x % PB;
    int tid  = threadIdx.x;

    for (int i = tid; i < 4 * SEG; i += 256) (&ls[0][0])[i] = 0ull;
    __syncthreads();

    const float* xb = x + (size_t)b * 3 * HW;
    const int*   sb = sl + (size_t)b * HW;
    int v0 = part * VCHUNK;

    for (int vi = tid; vi < VCHUNK; vi += 256) {
        int vg = v0 + vi;                 // float4 group index in image
        int4   id4 = ((const int4*)sb)[vg];
        float4 r4  = ((const float4*)xb)[vg];
        float4 g4  = ((const float4*)(xb + HW))[vg];
        float4 b4  = ((const float4*)(xb + 2 * HW))[vg];
        int p   = vg * 4;
        int row = p / IMGW;               // 4 | 224 -> all 4 pixels same row
        int col = p - row * IMGW;
        u64 rowbits = ((u64)1 << 48) | ((u64)(unsigned)row << 24);

#pragma unroll
        for (int q = 0; q < 4; ++q) {
            int   id = (q == 0) ? id4.x : (q == 1) ? id4.y : (q == 2) ? id4.z : id4.w;
            float r  = (q == 0) ? r4.x  : (q == 1) ? r4.y  : (q == 2) ? r4.z  : r4.w;
            float g  = (q == 0) ? g4.x  : (q == 1) ? g4.y  : (q == 2) ? g4.z  : g4.w;
            float bl = (q == 0) ? b4.x  : (q == 1) ? b4.y  : (q == 2) ? b4.z  : b4.w;

            unsigned qr  = (unsigned)fmaf(r,  8192.f, 131072.5f);   // (r+16)*8192
            unsigned qg  = (unsigned)fmaf(g,  8192.f, 131072.5f);
            unsigned qb  = (unsigned)fmaf(bl, 8192.f, 131072.5f);
            unsigned qr2 = (unsigned)fmaf(r * r,  2048.f, 0.5f);
            unsigned qg2 = (unsigned)fmaf(g * g,  2048.f, 0.5f);
            unsigned qb2 = (unsigned)fmaf(bl * bl, 2048.f, 0.5f);

            atomicAdd(&ls[0][id], rowbits | (unsigned)(col + q));
            atomicAdd(&ls[1][id], ((u64)qg  << 32) | qr);
            atomicAdd(&ls[2][id], ((u64)qr2 << 32) | qb);
            atomicAdd(&ls[3][id], ((u64)qb2 << 32) | qg2);
        }
    }
    __syncthreads();

    const float inv_s = 1.f / 8192.f, inv_q = 1.f / 2048.f;
    for (int i = tid; i < SEG; i += 256) {
        u64 v0p = ls[0][i];
        unsigned cnt = (unsigned)(v0p >> 48);
        if (!cnt) continue;
        float fc   = (float)cnt;
        float rows = (float)((unsigned)(v0p >> 24) & 0xFFFFFFu);
        float cols = (float)((unsigned)v0p & 0xFFFFFFu);
        u64 v1 = ls[1][i], v2 = ls[2][i], v3 = ls[3][i];
        float bias = 16.f * fc;
        float rsum = (float)(unsigned)v1         * inv_s - bias;
        float gsum = (float)(unsigned)(v1 >> 32) * inv_s - bias;
        float bsum = (float)(unsigned)v2         * inv_s - bias;
        float rsq  = (float)(unsigned)(v2 >> 32) * inv_q;
        float gsq  = (float)(unsigned)v3         * inv_q;
        float bsq  = (float)(unsigned)(v3 >> 32) * inv_q;

        size_t base = (size_t)b * SEG + i;
        atomicAdd(&stats[0 * NCOL + base], fc);
        atomicAdd(&stats[1 * NCOL + base], rows);
        atomicAdd(&stats[2 * NCOL + base], cols);
        atomicAdd(&stats[3 * NCOL + base], rsum);
        atomicAdd(&stats[4 * NCOL + base], gsum);
        atomicAdd(&stats[5 * NCOL + base], bsum);
        atomicAdd(&stats[6 * NCOL + base], rsq);
        atomicAdd(&stats[7 * NCOL + base], gsq);
        atomicAdd(&stats[8 * NCOL + base], bsq);
    }
}

// ---------------------------------------------------------------------------
// Kernel 3: weight convert fp32 (Cout,K) -> bf16 padded (Opad,Kpad), zero pads
// ---------------------------------------------------------------------------
__global__ __launch_bounds__(256) void convert_w(const float* __restrict__ src,
                                                 ushort* __restrict__ dst,
                                                 int Cout, int K, int Kpad, int total) {
    int i = blockIdx.x * 256 + threadIdx.x;
    if (i >= total) return;
    int o = i / Kpad, k = i - o * Kpad;
    float v = (o < Cout && k < K) ? src[(size_t)o * K + k] : 0.f;
    dst[i] = f2bf(v);
}

// ---------------------------------------------------------------------------
// Fused kernel: feat_build + L0 + L1 + L2 for a 64-row panel, activations
// resident in LDS, weights streamed from L2 cache (double-buffered tiles of
// 128o x 64k, source-XOR staging / read-XOR — same proven scheme as gemm_mfma).
// LDS map (ushort idx): W dbuf [0,16384) | F [16384,20480) | act0 [20480,28672)
//                       | act1 [28672,45056)  == 88 KB
// Output: L2 activations, plain row-major bf16 [NCOL][384] -> bufA (L3 input).
// ---------------------------------------------------------------------------
#define SH_W   0
#define SH_F   16384
#define SH_A0  20480
#define SH_A1  28672

__global__ __launch_bounds__(256) void fused_l012(
    const float* __restrict__ x,
    const float* __restrict__ stats,
    const ushort* __restrict__ W0g, const ushort* __restrict__ W1g, const ushort* __restrict__ W2g,
    const float* __restrict__ bias0, const float* __restrict__ gam0, const float* __restrict__ bet0,
    const float* __restrict__ rm0,  const float* __restrict__ rv0,
    const float* __restrict__ bias1, const float* __restrict__ gam1, const float* __restrict__ bet1,
    const float* __restrict__ rm1,  const float* __restrict__ rv1,
    const float* __restrict__ bias2, const float* __restrict__ gam2, const float* __restrict__ bet2,
    const float* __restrict__ rm2,  const float* __restrict__ rv2,
    ushort* __restrict__ outA)
{
    __shared__ ushort sh[45056];
    int tid  = threadIdx.x;
    int lane = tid & 63;
    int wid  = tid >> 6;
    int mrow = lane & 15;
    int quad = lane >> 4;
    int n0   = blockIdx.x * 64;

    // ---------------- feature phase: row r handled by thread r (r<64) -------
    if (tid < 64) {
        int r = tid, n = n0 + r;
        float cnt  = stats[n];
        float safe = fmaxf(cnt, 1.f);
        float inv  = 1.f / safe;
        float fmrow = stats[1 * NCOL + n] * inv;
        float fmcol = stats[2 * NCOL + n] * inv;
        float fmr   = stats[3 * NCOL + n] * inv;
        float fmg   = stats[4 * NCOL + n] * inv;
        float fmb   = stats[5 * NCOL + n] * inv;
        float den  = fmaxf(cnt - 1.f, 1.f);
        float vr = (stats[6 * NCOL + n] - cnt * fmr * fmr) / den;
        float vg = (stats[7 * NCOL + n] - cnt * fmg * fmg) / den;
        float vb = (stats[8 * NCOL + n] - cnt * fmb * fmb) / den;
        bool  has2 = cnt > 1.f;
        float sr = has2 ? sqrtf(fmaxf(vr, 0.f)) : 0.f;
        float sg = has2 ? sqrtf(fmaxf(vg, 0.f)) : 0.f;
        float sb = has2 ? sqrtf(fmaxf(vb, 0.f)) : 0.f;
        int b = n / SEG;
        int ri = min(max((int)fmrow, 0), IMGW - 1);
        int ci = min(max((int)fmcol, 0), IMGW - 1);
        const float* xb = x + (size_t)b * 3 * HW;
        int pi = ri * IMGW + ci;
        float gr = xb[pi], gg = xb[HW + pi], gb = xb[2 * HW + pi];
        float mask = cnt > 0.f ? 1.f : 0.f;

        int rx = r & 7;
        // group 0 (elems 0..7), stored at slot 0^rx
        bf16x8 v0;
        v0[0] = (short)f2bf(fmrow * mask);
        v0[1] = (short)f2bf(fmcol * mask);
        v0[2] = (short)f2bf(fmr * mask);
        v0[3] = (short)f2bf(fmg * mask);
        v0[4] = (short)f2bf(fmb * mask);
        v0[5] = (short)f2bf(sr * mask);
        v0[6] = (short)f2bf(sg * mask);
        v0[7] = (short)f2bf(sb * mask);
        *(bf16x8*)&sh[SH_F + r * 64 + (0 ^ rx) * 8] = v0;
        // group 1 (elems 8..10, rest zero), stored at slot 1^rx
        bf16x8 v1 = (bf16x8){0,0,0,0,0,0,0,0};
        v1[0] = (short)f2bf(gr * mask);
        v1[1] = (short)f2bf(gg * mask);
        v1[2] = (short)f2bf(gb * mask);
        *(bf16x8*)&sh[SH_F + r * 64 + (1 ^ rx) * 8] = v1;
        // groups 2..7 zero
        bf16x8 z = (bf16x8){0,0,0,0,0,0,0,0};
        for (int g = 2; g < 8; ++g)
            *(bf16x8*)&sh[SH_F + r * 64 + (g ^ rx) * 8] = z;
    }
    __syncthreads();

    // W tile staging: 128 rows x 64 k, XOR on SOURCE address, linear LDS dest.
    auto stageW = [&](int buf, int ot, int kt, const ushort* Wg, int Kl) {
#pragma unroll
        for (int p = 0; p < 4; ++p) {
            int flat = p * 256 + tid;
            int row = flat >> 3, kg = flat & 7;
            int kgs = kg ^ (row & 7);
            const ushort* gp = Wg + (size_t)(ot * 128 + row) * Kl + kt * 64 + kgs * 8;
            __builtin_amdgcn_global_load_lds(
                (const __attribute__((address_space(1))) void*)gp,
                (__attribute__((address_space(3))) void*)&sh[SH_W + buf * 8192 + (p * 256 + wid * 64) * 8],
                16, 0, 0);
        }
    };

    // One layer: A from LDS (aOff, row width Win elems), W streamed (KT*OT
    // tiles), out -> LDS (swizzled) or global (plain row-major 384).
    auto run_layer = [&](const ushort* Wg, int KT, int OT, int aOff, int Win,
                         const float* bb, const float* gg_, const float* bbe,
                         const float* rrm, const float* rrv, int CoutL,
                         int outOff, int Wout, int toGlobal, int Kl) {
        stageW(0, 0, 0, Wg, Kl);
        asm volatile("s_waitcnt vmcnt(0)" ::: "memory");
        __builtin_amdgcn_s_barrier();

        int T = OT * KT, cur = 0, ot = 0, kt = 0;
        f32x4 acc[4][2];
        float al[2], bt[2];
        for (int t = 0; t < T; ++t) {
            if (kt == 0) {
#pragma unroll
                for (int j = 0; j < 2; ++j) {
                    acc[0][j] = (f32x4){0.f, 0.f, 0.f, 0.f};
                    acc[1][j] = (f32x4){0.f, 0.f, 0.f, 0.f};
                    acc[2][j] = (f32x4){0.f, 0.f, 0.f, 0.f};
                    acc[3][j] = (f32x4){0.f, 0.f, 0.f, 0.f};
                    int o = ot * 128 + wid * 32 + j * 16 + mrow;
                    float a = 0.f, c = 0.f;
                    if (o < CoutL) {
                        float sc = gg_[o] / sqrtf(rrv[o] + 1e-5f);
                        a = sc;
                        c = (bb[o] - rrm[o]) * sc + bbe[o];
                    }
                    al[j] = a; bt[j] = c;
                }
            }
            if (t + 1 < T) {
                int kt2 = kt + 1, ot2 = ot;
                if (kt2 == KT) { kt2 = 0; ot2 = ot + 1; }
                stageW(cur ^ 1, ot2, kt2, Wg, Kl);
            }
#pragma unroll
            for (int ks = 0; ks < 2; ++ks) {
                bf16x8 af[4], bfr[2];
                int g = kt * 8 + ks * 4 + quad;
#pragma unroll
                for (int i = 0; i < 4; ++i) {
                    int row = i * 16 + mrow;
                    int slot = (g & ~7) | ((g ^ row) & 7);
                    af[i] = *(const bf16x8*)&sh[aOff + row * Win + slot * 8];
                }
#pragma unroll
                for (int j = 0; j < 2; ++j) {
                    int wrow = wid * 32 + j * 16 + mrow;
                    int wslot = (ks * 4 + quad) ^ (wrow & 7);
                    bfr[j] = *(const bf16x8*)&sh[SH_W + cur * 8192 + wrow * 64 + wslot * 8];
                }
#pragma unroll
                for (int i = 0; i < 4; ++i)
#pragma unroll
                    for (int j = 0; j < 2; ++j)
                        acc[i][j] = __builtin_amdgcn_mfma_f32_16x16x32_bf16(af[i], bfr[j], acc[i][j], 0, 0, 0);
            }
            if (t + 1 < T) {
                asm volatile("s_waitcnt vmcnt(0)" ::: "memory");
                __builtin_amdgcn_s_barrier();
            }
            if (kt == KT - 1) {
#pragma unroll
                for (int j = 0; j < 2; ++j) {
                    int o = ot * 128 + wid * 32 + j * 16 + mrow;
#pragma unroll
                    for (int i = 0; i < 4; ++i)
#pragma unroll
                        for (int rr = 0; rr < 4; ++rr) {
                            float v = fmaxf(acc[i][j][rr] * al[j] + bt[j], 0.f);
                            int row = i * 16 + quad * 4 + rr;
                            if (toGlobal) {
                                outA[(size_t)(n0 + row) * 384 + o] = f2bf(v);
                            } else {
                                int cg = o >> 3;
                                int slot = (cg & ~7) | ((cg ^ row) & 7);
                                sh[outOff + row * Wout + slot * 8 + (o & 7)] = f2bf(v);
                            }
                        }
                }
                kt = 0; ++ot;
            } else ++kt;
            cur ^= 1;
        }
        __syncthreads();   // actOut visible before next layer's A-reads
    };

    run_layer(W0g, 1, 1, SH_F,  64,  bias0, gam0, bet0, rm0, rv0,  96, SH_A0, 128, 0, 64);
    run_layer(W1g, 2, 2, SH_A0, 128, bias1, gam1, bet1, rm1, rv1, 192, SH_A1, 256, 0, 128);
    run_layer(W2g, 4, 3, SH_A1, 256, bias2, gam2, bet2, rm2, rv2, 384, 0,     384, 1, 256);
}

// ---------------------------------------------------------------------------
// Kernel 4: bf16 MFMA GEMM + folded BN (+ReLU), XOR-swizzled LDS (L3/L4).
// 2-phase double-buffer (proven round-2), bijective XCD swizzle, BN params
// hoisted above the K-loop so their gather latency hides under the loop.
// ---------------------------------------------------------------------------
__global__ __launch_bounds__(256) void gemm_mfma(const ushort* __restrict__ Aact,
                                                 const ushort* __restrict__ Wb,
                                                 void* __restrict__ outp,
                                                 const float* __restrict__ bias,
                                                 const float* __restrict__ gam,
                                                 const float* __restrict__ bet,
                                                 const float* __restrict__ rm,
                                                 const float* __restrict__ rv,
                                                 int Kpad, int Cout, int OutStride,
                                                 int act, int final_out) {
    __shared__ ushort As[2][128 * 64];   // [buf][n][k-slot]
    __shared__ ushort Bs[2][128 * 64];   // [buf][o][k-slot]

    int tid  = threadIdx.x;
    int lane = tid & 63;
    int wid  = tid >> 6;
    int wm   = wid & 1;               // wave row (n)
    int wn   = wid >> 1;              // wave col (o)

    // bijective XCD remap (m204)
    int nbx  = gridDim.x, nby = gridDim.y;
    int nwg  = nbx * nby;
    int orig = blockIdx.y * nbx + blockIdx.x;
    int xcd  = orig & 7;
    int q    = nwg >> 3, r = nwg & 7;
    int wgid = (xcd < r ? xcd * (q + 1) : r * (q + 1) + (xcd - r) * q) + (orig >> 3);
    int bx   = wgid / nby;            // row tile
    int by   = wgid - bx * nby;       // o tile
    int n0   = bx * 128;
    int o0   = by * 128;

    int mrow = lane & 15;
    int quad = lane >> 4;
    int swz  = mrow & 7;

    // BN fold hoisted: loads issue before the K-loop, latency hidden.
    float al4[4], bt4[4];
#pragma unroll
    for (int j = 0; j < 4; ++j) {
        int o = o0 + wn * 64 + j * 16 + mrow;
        float a = 0.f, c = 0.f;
        if (o < Cout) {
            float sc = gam[o] / sqrtf(rv[o] + 1e-5f);
            a = sc;
            c = (bias[o] - rm[o]) * sc + bet[o];
        }
        al4[j] = a; bt4[j] = c;
    }

    f32x4 acc[4][4];
#pragma unroll
    for (int i = 0; i < 4; ++i)
#pragma unroll
        for (int j = 0; j < 4; ++j) acc[i][j] = (f32x4){0.f, 0.f, 0.f, 0.f};

    const ushort* aSrc[4];
    const ushort* bSrc[4];
    int ldsDst[4];
#pragma unroll
    for (int p = 0; p < 4; ++p) {
        int flat = p * 256 + tid;
        int row  = flat >> 3, kg = flat & 7;
        int kgs  = kg ^ (row & 7);
        aSrc[p]  = Aact + (size_t)(n0 + row) * Kpad + kgs * 8;
        bSrc[p]  = Wb   + (size_t)(o0 + row) * Kpad + kgs * 8;
        ldsDst[p] = (p * 256 + wid * 64) * 8;
    }

    auto stage = [&](int buf, int kt) {
        int kb = kt * 64;
#pragma unroll
        for (int p = 0; p < 4; ++p)
            __builtin_amdgcn_global_load_lds(
                (const __attribute__((address_space(1))) void*)(aSrc[p] + kb),
                (__attribute__((address_space(3))) void*)(&As[buf][ldsDst[p]]),
                16, 0, 0);
#pragma unroll
        for (int p = 0; p < 4; ++p)
            __builtin_amdgcn_global_load_lds(
                (const __attribute__((address_space(1))) void*)(bSrc[p] + kb),
                (__attribute__((address_space(3))) void*)(&Bs[buf][ldsDst[p]]),
                16, 0, 0);
    };

    auto compute = [&](int buf) {
#pragma unroll
        for (int ks = 0; ks < 2; ++ks) {
            bf16x8 af[4], bfr[4];
            int gbase = ks * 4 + quad;
            int slot  = (gbase ^ swz) * 8;
#pragma unroll
            for (int i = 0; i < 4; ++i)
                af[i] = *(const bf16x8*)&As[buf][(size_t)(wm * 64 + i * 16 + mrow) * 64 + slot];
#pragma unroll
            for (int j = 0; j < 4; ++j)
                bfr[j] = *(const bf16x8*)&Bs[buf][(size_t)(wn * 64 + j * 16 + mrow) * 64 + slot];
#pragma unroll
            for (int i = 0; i < 4; ++i)
#pragma unroll
                for (int j = 0; j < 4; ++j)
                    acc[i][j] = __builtin_amdgcn_mfma_f32_16x16x32_bf16(af[i], bfr[j], acc[i][j], 0, 0, 0);
        }
    };

    int ktiles = Kpad >> 6;

    stage(0, 0);
    asm volatile("s_waitcnt vmcnt(0)" ::: "memory");
    __builtin_amdgcn_s_barrier();

    int cur = 0;
    for (int t = 0; t < ktiles - 1; ++t) {
        stage(cur ^ 1, t + 1);
        compute(cur);
        asm volatile("s_waitcnt vmcnt(0)" ::: "memory");
        __builtin_amdgcn_s_barrier();
        cur ^= 1;
    }
    compute(cur);

#pragma unroll
    for (int j = 0; j < 4; ++j) {
        int o = o0 + wn * 64 + j * 16 + mrow;
#pragma unroll
        for (int i = 0; i < 4; ++i) {
            int nbase = n0 + wm * 64 + i * 16 + quad * 4;
#pragma unroll
            for (int rr = 0; rr < 4; ++rr) {
                float v = acc[i][j][rr] * al4[j] + bt4[j];
                if (act) v = fmaxf(v, 0.f);
                int n = nbase + rr;
                if (final_out) {
                    int b = n / SEG, s = n - b * SEG;
                    ((float*)outp)[(size_t)b * 768 * SEG + (size_t)o * SEG + s] = v;
                } else {
                    ((ushort*)outp)[(size_t)n * OutStride + o] = f2bf(v);
                }
            }
        }
    }
}

// ---------------------------------------------------------------------------
// Kernel 5: copy sliced (int32) -> out as float values
// ---------------------------------------------------------------------------
__global__ __launch_bounds__(256) void copy_sliced(const int4* __restrict__ sl,
                                                   float4* __restrict__ out) {
    int i = blockIdx.x * 256 + threadIdx.x;
    int4 v = sl[i];
    out[i] = make_float4((float)v.x, (float)v.y, (float)v.z, (float)v.w);
}

// ---------------------------------------------------------------------------
extern "C" void kernel_launch(void* const* d_in, const int* in_sizes, int n_in,
                              void* d_out, int out_size, void* d_ws, size_t ws_size,
                              hipStream_t stream) {
    const float* x  = (const float*)d_in[0];
    const int*   sl = (const int*)d_in[1];
    const float* Wp[5], *Bp[5], *Gp[5], *BEp[5], *RMp[5], *RVp[5];
    for (int i = 0; i < 5; ++i) {
        Wp[i]  = (const float*)d_in[2 + 6 * i + 0];
        Bp[i]  = (const float*)d_in[2 + 6 * i + 1];
        Gp[i]  = (const float*)d_in[2 + 6 * i + 2];
        BEp[i] = (const float*)d_in[2 + 6 * i + 3];
        RMp[i] = (const float*)d_in[2 + 6 * i + 4];
        RVp[i] = (const float*)d_in[2 + 6 * i + 5];
    }
    float* out = (float*)d_out;

    // layer geometry: Kpad (=prev Opad), Kreal, Cout, Opad
    const int Kpad[5]  = {64, 128, 256, 384, 768};
    const int Kreal[5] = {11, 96, 192, 384, 768};
    const int Cout[5]  = {96, 192, 384, 768, 768};
    const int Opad[5]  = {128, 256, 384, 768, 768};

    // workspace layout (unchanged; F region now unused but kept)
    char* wsb = (char*)d_ws;
    float*  stats = (float*)wsb;                        // 9*NCOL fp32
    wsb += (size_t)9 * NCOL * sizeof(float);
    ushort* F = (ushort*)wsb;                           // NCOL x 64 bf16 (unused)
    wsb += (size_t)NCOL * 64 * sizeof(ushort);
    ushort* Wpad[5];
    for (int i = 0; i < 5; ++i) {
        Wpad[i] = (ushort*)wsb;
        wsb += (size_t)Opad[i] * Kpad[i] * sizeof(ushort);
    }
    ushort* bufA = (ushort*)wsb;                        // NCOL x 384 bf16 max
    wsb += (size_t)NCOL * 384 * sizeof(ushort);
    ushort* bufB = (ushort*)wsb;                        // NCOL x 768 bf16
    (void)F;

    hipMemsetAsync(stats, 0, (size_t)9 * NCOL * sizeof(float), stream);

    for (int i = 0; i < 5; ++i) {
        int total = Opad[i] * Kpad[i];
        convert_w<<<(total + 255) / 256, 256, 0, stream>>>(
            Wp[i], Wpad[i], Cout[i], Kreal[i], Kpad[i], total);
    }

    seg_accum<<<NBATCH * PB, 256, 0, stream>>>(x, sl, stats);

    // Fused feat + L0 + L1 + L2 -> bufA (NCOL x 384 bf16, plain row-major)
    fused_l012<<<NCOL / 64, 256, 0, stream>>>(
        x, stats, Wpad[0], Wpad[1], Wpad[2],
        Bp[0], Gp[0], BEp[0], RMp[0], RVp[0],
        Bp[1], Gp[1], BEp[1], RMp[1], RVp[1],
        Bp[2], Gp[2], BEp[2], RMp[2], RVp[2],
        bufA);

    const int NT = NCOL / 128;  // 196 row tiles
    // L3: 384 -> 768, relu
    gemm_mfma<<<dim3(NT, Opad[3] / 128), 256, 0, stream>>>(
        bufA, Wpad[3], bufB, Bp[3], Gp[3], BEp[3], RMp[3], RVp[3],
        Kpad[3], Cout[3], Opad[3], 1, 0);
    // L4: 768 -> 768, no act, fp32 out at offset B*H*W in (b,768,196) layout
    gemm_mfma<<<dim3(NT, Opad[4] / 128), 256, 0, stream>>>(
        bufB, Wpad[4], out + (size_t)NBATCH * HW, Bp[4], Gp[4], BEp[4], RMp[4], RVp[4],
        Kpad[4], Cout[4], 0, 0, 1);

    // output 0: sliced as float
    copy_sliced<<<(NBATCH * HW / 4) / 256, 256, 0, stream>>>((const int4*)sl,
                                                             (float4*)out);
}

// Round 5
// 401.258 us; speedup vs baseline: 1.0294x; 1.0243x over previous
//
#include <hip/hip_runtime.h>
#include <hip/hip_bf16.h>

// Problem constants
#define HW    50176            // 224*224
#define IMGW  224
#define SEG   196              // R*R
#define NBATCH 128
#define NCOL  (NBATCH * SEG)   // 25088 rows (pixels) of every GEMM
#define PB    14               // accumulation blocks per batch image
#define CHUNK (HW / PB)        // 3584 pixels per block
#define VCHUNK (CHUNK / 4)     // 896 float4 groups per block

typedef __attribute__((ext_vector_type(8))) short bf16x8;   // 8 bf16 = 4 VGPRs
typedef __attribute__((ext_vector_type(4))) float f32x4;
typedef unsigned long long u64;

static __device__ __forceinline__ ushort f2bf(float v) {
    __hip_bfloat16 h = __float2bfloat16(v);
    return *reinterpret_cast<ushort*>(&h);
}

// ---------------------------------------------------------------------------
// Kernel 1: segmented accumulation via packed u64 LDS atomics (4 per pixel).
// Also emits float(sliced) into out[0..NBATCH*HW) — id4 already in registers,
// so the former copy_sliced dispatch (and its 25.7 MB re-read) is free here.
// ---------------------------------------------------------------------------
__global__ __launch_bounds__(256) void seg_accum(const float* __restrict__ x,
                                                 const int*   __restrict__ sl,
                                                 float*       __restrict__ stats,
                                                 float*       __restrict__ outf) {
    __shared__ u64 ls[4][SEG];
    int b    = blockIdx.x / PB;
    int part = blockIdx.x % PB;
    int tid  = threadIdx.x;

    for (int i = tid; i < 4 * SEG; i += 256) (&ls[0][0])[i] = 0ull;
    __syncthreads();

    const float* xb = x + (size_t)b * 3 * HW;
    const int*   sb = sl + (size_t)b * HW;
    float4*      ob = (float4*)(outf + (size_t)b * HW);
    int v0 = part * VCHUNK;

    for (int vi = tid; vi < VCHUNK; vi += 256) {
        int vg = v0 + vi;                 // float4 group index in image
        int4   id4 = ((const int4*)sb)[vg];
        float4 r4  = ((const float4*)xb)[vg];
        float4 g4  = ((const float4*)(xb + HW))[vg];
        float4 b4  = ((const float4*)(xb + 2 * HW))[vg];

        // fused copy_sliced: float conversion of the ids
        ob[vg] = make_float4((float)id4.x, (float)id4.y, (float)id4.z, (float)id4.w);

        int p   = vg * 4;
        int row = p / IMGW;               // 4 | 224 -> all 4 pixels same row
        int col = p - row * IMGW;
        u64 rowbits = ((u64)1 << 48) | ((u64)(unsigned)row << 24);

#pragma unroll
        for (int q = 0; q < 4; ++q) {
            int   id = (q == 0) ? id4.x : (q == 1) ? id4.y : (q == 2) ? id4.z : id4.w;
            float r  = (q == 0) ? r4.x  : (q == 1) ? r4.y  : (q == 2) ? r4.z  : r4.w;
            float g  = (q == 0) ? g4.x  : (q == 1) ? g4.y  : (q == 2) ? g4.z  : g4.w;
            float bl = (q == 0) ? b4.x  : (q == 1) ? b4.y  : (q == 2) ? b4.z  : b4.w;

            unsigned qr  = (unsigned)fmaf(r,  8192.f, 131072.5f);   // (r+16)*8192
            unsigned qg  = (unsigned)fmaf(g,  8192.f, 131072.5f);
            unsigned qb  = (unsigned)fmaf(bl, 8192.f, 131072.5f);
            unsigned qr2 = (unsigned)fmaf(r * r,  2048.f, 0.5f);
            unsigned qg2 = (unsigned)fmaf(g * g,  2048.f, 0.5f);
            unsigned qb2 = (unsigned)fmaf(bl * bl, 2048.f, 0.5f);

            atomicAdd(&ls[0][id], rowbits | (unsigned)(col + q));
            atomicAdd(&ls[1][id], ((u64)qg  << 32) | qr);
            atomicAdd(&ls[2][id], ((u64)qr2 << 32) | qb);
            atomicAdd(&ls[3][id], ((u64)qb2 << 32) | qg2);
        }
    }
    __syncthreads();

    const float inv_s = 1.f / 8192.f, inv_q = 1.f / 2048.f;
    for (int i = tid; i < SEG; i += 256) {
        u64 v0p = ls[0][i];
        unsigned cnt = (unsigned)(v0p >> 48);
        if (!cnt) continue;
        float fc   = (float)cnt;
        float rows = (float)((unsigned)(v0p >> 24) & 0xFFFFFFu);
        float cols = (float)((unsigned)v0p & 0xFFFFFFu);
        u64 v1 = ls[1][i], v2 = ls[2][i], v3 = ls[3][i];
        float bias = 16.f * fc;
        float rsum = (float)(unsigned)v1         * inv_s - bias;
        float gsum = (float)(unsigned)(v1 >> 32) * inv_s - bias;
        float bsum = (float)(unsigned)v2         * inv_s - bias;
        float rsq  = (float)(unsigned)(v2 >> 32) * inv_q;
        float gsq  = (float)(unsigned)v3         * inv_q;
        float bsq  = (float)(unsigned)(v3 >> 32) * inv_q;

        size_t base = (size_t)b * SEG + i;
        atomicAdd(&stats[0 * NCOL + base], fc);
        atomicAdd(&stats[1 * NCOL + base], rows);
        atomicAdd(&stats[2 * NCOL + base], cols);
        atomicAdd(&stats[3 * NCOL + base], rsum);
        atomicAdd(&stats[4 * NCOL + base], gsum);
        atomicAdd(&stats[5 * NCOL + base], bsum);
        atomicAdd(&stats[6 * NCOL + base], rsq);
        atomicAdd(&stats[7 * NCOL + base], gsq);
        atomicAdd(&stats[8 * NCOL + base], bsq);
    }
}

// ---------------------------------------------------------------------------
// Kernel: all 5 weight conversions in ONE dispatch (block-range switch).
// elems/256: L0 32 | L1 128 | L2 384 | L3 1152 | L4 2304 -> 4000 blocks.
// ---------------------------------------------------------------------------
__global__ __launch_bounds__(256) void convert_all(
    const float* __restrict__ s0, const float* __restrict__ s1,
    const float* __restrict__ s2, const float* __restrict__ s3,
    const float* __restrict__ s4,
    ushort* __restrict__ d0, ushort* __restrict__ d1, ushort* __restrict__ d2,
    ushort* __restrict__ d3, ushort* __restrict__ d4) {
    int blk = blockIdx.x;
    const float* src; ushort* dst; int Cout, K, Kpad, base;
    if (blk < 32)        { src = s0; dst = d0; Cout = 96;  K = 11;  Kpad = 64;  base = 0;    }
    else if (blk < 160)  { src = s1; dst = d1; Cout = 192; K = 96;  Kpad = 128; base = 32;   }
    else if (blk < 544)  { src = s2; dst = d2; Cout = 384; K = 192; Kpad = 256; base = 160;  }
    else if (blk < 1696) { src = s3; dst = d3; Cout = 768; K = 384; Kpad = 384; base = 544;  }
    else                 { src = s4; dst = d4; Cout = 768; K = 768; Kpad = 768; base = 1696; }
    int i = (blk - base) * 256 + threadIdx.x;
    int o = i / Kpad, k = i - o * Kpad;
    float v = (o < Cout && k < K) ? src[(size_t)o * K + k] : 0.f;
    dst[i] = f2bf(v);
}

// ---------------------------------------------------------------------------
// Fused kernel: feat_build + L0 + L1 + L2 for a 64-row panel, activations
// resident in LDS, weights streamed from L2 cache (double-buffered tiles of
// 128o x 64k, source-XOR staging / read-XOR).  UNCHANGED (passing since r3).
// LDS map (ushort idx): W dbuf [0,16384) | F [16384,20480) | act0 [20480,28672)
//                       | act1 [28672,45056)  == 88 KB
// ---------------------------------------------------------------------------
#define SH_W   0
#define SH_F   16384
#define SH_A0  20480
#define SH_A1  28672

__global__ __launch_bounds__(256) void fused_l012(
    const float* __restrict__ x,
    const float* __restrict__ stats,
    const ushort* __restrict__ W0g, const ushort* __restrict__ W1g, const ushort* __restrict__ W2g,
    const float* __restrict__ bias0, const float* __restrict__ gam0, const float* __restrict__ bet0,
    const float* __restrict__ rm0,  const float* __restrict__ rv0,
    const float* __restrict__ bias1, const float* __restrict__ gam1, const float* __restrict__ bet1,
    const float* __restrict__ rm1,  const float* __restrict__ rv1,
    const float* __restrict__ bias2, const float* __restrict__ gam2, const float* __restrict__ bet2,
    const float* __restrict__ rm2,  const float* __restrict__ rv2,
    ushort* __restrict__ outA)
{
    __shared__ ushort sh[45056];
    int tid  = threadIdx.x;
    int lane = tid & 63;
    int wid  = tid >> 6;
    int mrow = lane & 15;
    int quad = lane >> 4;
    int n0   = blockIdx.x * 64;

    // ---------------- feature phase: row r handled by thread r (r<64) -------
    if (tid < 64) {
        int r = tid, n = n0 + r;
        float cnt  = stats[n];
        float safe = fmaxf(cnt, 1.f);
        float inv  = 1.f / safe;
        float fmrow = stats[1 * NCOL + n] * inv;
        float fmcol = stats[2 * NCOL + n] * inv;
        float fmr   = stats[3 * NCOL + n] * inv;
        float fmg   = stats[4 * NCOL + n] * inv;
        float fmb   = stats[5 * NCOL + n] * inv;
        float den  = fmaxf(cnt - 1.f, 1.f);
        float vr = (stats[6 * NCOL + n] - cnt * fmr * fmr) / den;
        float vg = (stats[7 * NCOL + n] - cnt * fmg * fmg) / den;
        float vb = (stats[8 * NCOL + n] - cnt * fmb * fmb) / den;
        bool  has2 = cnt > 1.f;
        float sr = has2 ? sqrtf(fmaxf(vr, 0.f)) : 0.f;
        float sg = has2 ? sqrtf(fmaxf(vg, 0.f)) : 0.f;
        float sb = has2 ? sqrtf(fmaxf(vb, 0.f)) : 0.f;
        int b = n / SEG;
        int ri = min(max((int)fmrow, 0), IMGW - 1);
        int ci = min(max((int)fmcol, 0), IMGW - 1);
        const float* xb = x + (size_t)b * 3 * HW;
        int pi = ri * IMGW + ci;
        float gr = xb[pi], gg = xb[HW + pi], gb = xb[2 * HW + pi];
        float mask = cnt > 0.f ? 1.f : 0.f;

        int rx = r & 7;
        // group 0 (elems 0..7), stored at slot 0^rx
        bf16x8 v0;
        v0[0] = (short)f2bf(fmrow * mask);
        v0[1] = (short)f2bf(fmcol * mask);
        v0[2] = (short)f2bf(fmr * mask);
        v0[3] = (short)f2bf(fmg * mask);
        v0[4] = (short)f2bf(fmb * mask);
        v0[5] = (short)f2bf(sr * mask);
        v0[6] = (short)f2bf(sg * mask);
        v0[7] = (short)f2bf(sb * mask);
        *(bf16x8*)&sh[SH_F + r * 64 + (0 ^ rx) * 8] = v0;
        // group 1 (elems 8..10, rest zero), stored at slot 1^rx
        bf16x8 v1 = (bf16x8){0,0,0,0,0,0,0,0};
        v1[0] = (short)f2bf(gr * mask);
        v1[1] = (short)f2bf(gg * mask);
        v1[2] = (short)f2bf(gb * mask);
        *(bf16x8*)&sh[SH_F + r * 64 + (1 ^ rx) * 8] = v1;
        // groups 2..7 zero
        bf16x8 z = (bf16x8){0,0,0,0,0,0,0,0};
        for (int g = 2; g < 8; ++g)
            *(bf16x8*)&sh[SH_F + r * 64 + (g ^ rx) * 8] = z;
    }
    __syncthreads();

    // W tile staging: 128 rows x 64 k, XOR on SOURCE address, linear LDS dest.
    auto stageW = [&](int buf, int ot, int kt, const ushort* Wg, int Kl) {
#pragma unroll
        for (int p = 0; p < 4; ++p) {
            int flat = p * 256 + tid;
            int row = flat >> 3, kg = flat & 7;
            int kgs = kg ^ (row & 7);
            const ushort* gp = Wg + (size_t)(ot * 128 + row) * Kl + kt * 64 + kgs * 8;
            __builtin_amdgcn_global_load_lds(
                (const __attribute__((address_space(1))) void*)gp,
                (__attribute__((address_space(3))) void*)&sh[SH_W + buf * 8192 + (p * 256 + wid * 64) * 8],
                16, 0, 0);
        }
    };

    // One layer: A from LDS (aOff, row width Win elems), W streamed (KT*OT
    // tiles), out -> LDS (swizzled) or global (plain row-major 384).
    auto run_layer = [&](const ushort* Wg, int KT, int OT, int aOff, int Win,
                         const float* bb, const float* gg_, const float* bbe,
                         const float* rrm, const float* rrv, int CoutL,
                         int outOff, int Wout, int toGlobal, int Kl) {
        stageW(0, 0, 0, Wg, Kl);
        asm volatile("s_waitcnt vmcnt(0)" ::: "memory");
        __builtin_amdgcn_s_barrier();

        int T = OT * KT, cur = 0, ot = 0, kt = 0;
        f32x4 acc[4][2];
        float al[2], bt[2];
        for (int t = 0; t < T; ++t) {
            if (kt == 0) {
#pragma unroll
                for (int j = 0; j < 2; ++j) {
                    acc[0][j] = (f32x4){0.f, 0.f, 0.f, 0.f};
                    acc[1][j] = (f32x4){0.f, 0.f, 0.f, 0.f};
                    acc[2][j] = (f32x4){0.f, 0.f, 0.f, 0.f};
                    acc[3][j] = (f32x4){0.f, 0.f, 0.f, 0.f};
                    int o = ot * 128 + wid * 32 + j * 16 + mrow;
                    float a = 0.f, c = 0.f;
                    if (o < CoutL) {
                        float sc = gg_[o] / sqrtf(rrv[o] + 1e-5f);
                        a = sc;
                        c = (bb[o] - rrm[o]) * sc + bbe[o];
                    }
                    al[j] = a; bt[j] = c;
                }
            }
            if (t + 1 < T) {
                int kt2 = kt + 1, ot2 = ot;
                if (kt2 == KT) { kt2 = 0; ot2 = ot + 1; }
                stageW(cur ^ 1, ot2, kt2, Wg, Kl);
            }
#pragma unroll
            for (int ks = 0; ks < 2; ++ks) {
                bf16x8 af[4], bfr[2];
                int g = kt * 8 + ks * 4 + quad;
#pragma unroll
                for (int i = 0; i < 4; ++i) {
                    int row = i * 16 + mrow;
                    int slot = (g & ~7) | ((g ^ row) & 7);
                    af[i] = *(const bf16x8*)&sh[aOff + row * Win + slot * 8];
                }
#pragma unroll
                for (int j = 0; j < 2; ++j) {
                    int wrow = wid * 32 + j * 16 + mrow;
                    int wslot = (ks * 4 + quad) ^ (wrow & 7);
                    bfr[j] = *(const bf16x8*)&sh[SH_W + cur * 8192 + wrow * 64 + wslot * 8];
                }
#pragma unroll
                for (int i = 0; i < 4; ++i)
#pragma unroll
                    for (int j = 0; j < 2; ++j)
                        acc[i][j] = __builtin_amdgcn_mfma_f32_16x16x32_bf16(af[i], bfr[j], acc[i][j], 0, 0, 0);
            }
            if (t + 1 < T) {
                asm volatile("s_waitcnt vmcnt(0)" ::: "memory");
                __builtin_amdgcn_s_barrier();
            }
            if (kt == KT - 1) {
#pragma unroll
                for (int j = 0; j < 2; ++j) {
                    int o = ot * 128 + wid * 32 + j * 16 + mrow;
#pragma unroll
                    for (int i = 0; i < 4; ++i)
#pragma unroll
                        for (int rr = 0; rr < 4; ++rr) {
                            float v = fmaxf(acc[i][j][rr] * al[j] + bt[j], 0.f);
                            int row = i * 16 + quad * 4 + rr;
                            if (toGlobal) {
                                outA[(size_t)(n0 + row) * 384 + o] = f2bf(v);
                            } else {
                                int cg = o >> 3;
                                int slot = (cg & ~7) | ((cg ^ row) & 7);
                                sh[outOff + row * Wout + slot * 8 + (o & 7)] = f2bf(v);
                            }
                        }
                }
                kt = 0; ++ot;
            } else ++kt;
            cur ^= 1;
        }
        __syncthreads();   // actOut visible before next layer's A-reads
    };

    run_layer(W0g, 1, 1, SH_F,  64,  bias0, gam0, bet0, rm0, rv0,  96, SH_A0, 128, 0, 64);
    run_layer(W1g, 2, 2, SH_A0, 128, bias1, gam1, bet1, rm1, rv1, 192, SH_A1, 256, 0, 128);
    run_layer(W2g, 4, 3, SH_A1, 256, bias2, gam2, bet2, rm2, rv2, 384, 0,     384, 1, 256);
}

// ---------------------------------------------------------------------------
// Kernel 4: bf16 MFMA GEMM + folded BN (+ReLU), XOR-swizzled LDS.
// EXACT round-0 configuration (measured 80.5 us on L4): single 32KB buffer,
// __syncthreads K-loop, natural block order, BN in epilogue, plain
// __launch_bounds__(256).
// ---------------------------------------------------------------------------
__global__ __launch_bounds__(256) void gemm_mfma(const ushort* __restrict__ Aact,
                                                 const ushort* __restrict__ Wb,
                                                 void* __restrict__ outp,
                                                 const float* __restrict__ bias,
                                                 const float* __restrict__ gam,
                                                 const float* __restrict__ bet,
                                                 const float* __restrict__ rm,
                                                 const float* __restrict__ rv,
                                                 int Kpad, int Cout, int OutStride,
                                                 int act, int final_out) {
    __shared__ ushort As[128 * 64];   // [n][k-slot]
    __shared__ ushort Bs[128 * 64];   // [o][k-slot]

    int tid  = threadIdx.x;
    int lane = tid & 63;
    int wid  = tid >> 6;
    int wm   = wid & 1;               // wave row (n)
    int wn   = wid >> 1;              // wave col (o)
    int n0   = blockIdx.x * 128;
    int o0   = blockIdx.y * 128;
    int mrow = lane & 15;
    int quad = lane >> 4;
    int swz  = mrow & 7;              // row-dependent XOR for fragment reads

    f32x4 acc[4][4];
#pragma unroll
    for (int i = 0; i < 4; ++i)
#pragma unroll
        for (int j = 0; j < 4; ++j) acc[i][j] = (f32x4){0.f, 0.f, 0.f, 0.f};

    int ktiles = Kpad >> 6;
    for (int kt = 0; kt < ktiles; ++kt) {
        int kb = kt * 64;
        // stage A tile: 128 rows x 64 k, 16B per lane, 4 passes, swizzled source
#pragma unroll
        for (int p = 0; p < 4; ++p) {
            int flat = p * 256 + tid;
            int row = flat >> 3, kg = flat & 7;
            int kgs = kg ^ (row & 7);
            const ushort* gp = Aact + (size_t)(n0 + row) * Kpad + kb + kgs * 8;
            __builtin_amdgcn_global_load_lds(
                (const __attribute__((address_space(1))) void*)gp,
                (__attribute__((address_space(3))) void*)(As + (size_t)(p * 256 + wid * 64) * 8),
                16, 0, 0);
        }
        // stage B tile (weights), swizzled source
#pragma unroll
        for (int p = 0; p < 4; ++p) {
            int flat = p * 256 + tid;
            int row = flat >> 3, kg = flat & 7;
            int kgs = kg ^ (row & 7);
            const ushort* gp = Wb + (size_t)(o0 + row) * Kpad + kb + kgs * 8;
            __builtin_amdgcn_global_load_lds(
                (const __attribute__((address_space(1))) void*)gp,
                (__attribute__((address_space(3))) void*)(Bs + (size_t)(p * 256 + wid * 64) * 8),
                16, 0, 0);
        }
        __syncthreads();

#pragma unroll
        for (int ks = 0; ks < 2; ++ks) {
            bf16x8 af[4], bfr[4];
            int gbase = ks * 4 + quad;           // logical 16B group 0..7
            int slot  = (gbase ^ swz) * 8;       // swizzled element offset
#pragma unroll
            for (int i = 0; i < 4; ++i)
                af[i] = *(const bf16x8*)&As[(size_t)(wm * 64 + i * 16 + mrow) * 64 + slot];
#pragma unroll
            for (int j = 0; j < 4; ++j)
                bfr[j] = *(const bf16x8*)&Bs[(size_t)(wn * 64 + j * 16 + mrow) * 64 + slot];
#pragma unroll
            for (int i = 0; i < 4; ++i)
#pragma unroll
                for (int j = 0; j < 4; ++j)
                    acc[i][j] = __builtin_amdgcn_mfma_f32_16x16x32_bf16(af[i], bfr[j], acc[i][j], 0, 0, 0);
        }
        __syncthreads();
    }

    // epilogue: C row = n (quad*4+reg), col = o (lane&15)
#pragma unroll
    for (int j = 0; j < 4; ++j) {
        int o = o0 + wn * 64 + j * 16 + mrow;
        float al = 0.f, bt = 0.f;
        if (o < Cout) {
            float sc = gam[o] / sqrtf(rv[o] + 1e-5f);
            al = sc;
            bt = (bias[o] - rm[o]) * sc + bet[o];
        }
#pragma unroll
        for (int i = 0; i < 4; ++i) {
            int nbase = n0 + wm * 64 + i * 16 + quad * 4;
#pragma unroll
            for (int r = 0; r < 4; ++r) {
                float v = acc[i][j][r] * al + bt;
                if (act) v = fmaxf(v, 0.f);
                int n = nbase + r;
                if (final_out) {
                    int b = n / SEG, s = n - b * SEG;
                    ((float*)outp)[(size_t)b * 768 * SEG + (size_t)o * SEG + s] = v;
                } else {
                    ((ushort*)outp)[(size_t)n * OutStride + o] = f2bf(v);
                }
            }
        }
    }
}

// ---------------------------------------------------------------------------
extern "C" void kernel_launch(void* const* d_in, const int* in_sizes, int n_in,
                              void* d_out, int out_size, void* d_ws, size_t ws_size,
                              hipStream_t stream) {
    const float* x  = (const float*)d_in[0];
    const int*   sl = (const int*)d_in[1];
    const float* Wp[5], *Bp[5], *Gp[5], *BEp[5], *RMp[5], *RVp[5];
    for (int i = 0; i < 5; ++i) {
        Wp[i]  = (const float*)d_in[2 + 6 * i + 0];
        Bp[i]  = (const float*)d_in[2 + 6 * i + 1];
        Gp[i]  = (const float*)d_in[2 + 6 * i + 2];
        BEp[i] = (const float*)d_in[2 + 6 * i + 3];
        RMp[i] = (const float*)d_in[2 + 6 * i + 4];
        RVp[i] = (const float*)d_in[2 + 6 * i + 5];
    }
    float* out = (float*)d_out;

    // layer geometry: Kpad (=prev Opad), Kreal, Cout, Opad
    const int Kpad[5]  = {64, 128, 256, 384, 768};
    const int Cout[5]  = {96, 192, 384, 768, 768};
    const int Opad[5]  = {128, 256, 384, 768, 768};

    // workspace layout (unchanged; F region kept for layout stability)
    char* wsb = (char*)d_ws;
    float*  stats = (float*)wsb;                        // 9*NCOL fp32
    wsb += (size_t)9 * NCOL * sizeof(float);
    ushort* F = (ushort*)wsb;                           // NCOL x 64 bf16 (unused)
    wsb += (size_t)NCOL * 64 * sizeof(ushort);
    ushort* Wpad[5];
    for (int i = 0; i < 5; ++i) {
        Wpad[i] = (ushort*)wsb;
        wsb += (size_t)Opad[i] * Kpad[i] * sizeof(ushort);
    }
    ushort* bufA = (ushort*)wsb;                        // NCOL x 384 bf16 max
    wsb += (size_t)NCOL * 384 * sizeof(ushort);
    ushort* bufB = (ushort*)wsb;                        // NCOL x 768 bf16
    (void)F;

    hipMemsetAsync(stats, 0, (size_t)9 * NCOL * sizeof(float), stream);

    // all weight conversions in one dispatch (was 5)
    convert_all<<<4000, 256, 0, stream>>>(
        Wp[0], Wp[1], Wp[2], Wp[3], Wp[4],
        Wpad[0], Wpad[1], Wpad[2], Wpad[3], Wpad[4]);

    // seg stats + fused sliced->float copy (was 2 dispatches)
    seg_accum<<<NBATCH * PB, 256, 0, stream>>>(x, sl, stats, out);

    // Fused feat + L0 + L1 + L2 -> bufA (NCOL x 384 bf16, plain row-major)
    fused_l012<<<NCOL / 64, 256, 0, stream>>>(
        x, stats, Wpad[0], Wpad[1], Wpad[2],
        Bp[0], Gp[0], BEp[0], RMp[0], RVp[0],
        Bp[1], Gp[1], BEp[1], RMp[1], RVp[1],
        Bp[2], Gp[2], BEp[2], RMp[2], RVp[2],
        bufA);

    const int NT = NCOL / 128;  // 196 row tiles
    // L3: 384 -> 768, relu
    gemm_mfma<<<dim3(NT, Opad[3] / 128), 256, 0, stream>>>(
        bufA, Wpad[3], bufB, Bp[3], Gp[3], BEp[3], RMp[3], RVp[3],
        Kpad[3], Cout[3], Opad[3], 1, 0);
    // L4: 768 -> 768, no act, fp32 out at offset B*H*W in (b,768,196) layout
    gemm_mfma<<<dim3(NT, Opad[4] / 128), 256, 0, stream>>>(
        bufB, Wpad[4], out + (size_t)NBATCH * HW, Bp[4], Gp[4], BEp[4], RMp[4], RVp[4],
        Kpad[4], Cout[4], 0, 0, 1);
}